// Round 10
// baseline (223.165 us; speedup 1.0000x reference)
//
#include <hip/hip_runtime.h>

#define N_NODES 100000
#define N_EDGES 1600000
#define IN_DIM  128
#define HIDDEN  128
#define OUT_DIM 64

#define BUCK_SHIFT 6                          // 64-node buckets
#define BUCK_SZ    64
#define NB_BUCK ((N_NODES + BUCK_SZ - 1) / BUCK_SZ)   // 1563 buckets
#define EPB 4096                              // edges per partition block (R1-proven)
#define NBLK_E ((N_EDGES + EPB - 1) / EPB)    // 391 partition blocks
#define GB1 ((N_NODES + 127) / 128)           // 782 GEMM1 blocks
#define CAP 1536                              // bucket capacity (mean 1024 + 16 sigma)
#define PCAP 1984                             // padded capacity, mult of 8
#define CSTR 16                               // cursor stride (ints): one counter per 64B line

typedef __attribute__((ext_vector_type(8))) short bf8_t;   // 8 x bf16 (4 VGPRs)
typedef __attribute__((ext_vector_type(4))) float f4_t;    // MFMA accumulator

__device__ __forceinline__ ushort f2b(float f) {           // fp32 -> bf16 RNE
    unsigned int u = __float_as_uint(f);
    u += 0x7fffu + ((u >> 16) & 1u);
    return (ushort)(u >> 16);
}
__device__ __forceinline__ float b2f_lo(unsigned int u) { return __uint_as_float(u << 16); }
__device__ __forceinline__ float b2f_hi(unsigned int u) { return __uint_as_float(u & 0xffff0000u); }

// ---- k_prep: w1b conversion + cursor zero (now 100KB, line-strided) + sentinels ----
__global__ __launch_bounds__(256) void k_prep(const float* __restrict__ W1,
                                              ushort* __restrict__ w1b,
                                              int* __restrict__ cursor,
                                              float* __restrict__ dinv,
                                              ushort* __restrict__ h) {
    int b = blockIdx.x, t = threadIdx.x;
    if (b < 8) {
        int start = b * 2048;
        #pragma unroll
        for (int j = 0; j < 8; j++) {
            int i = start + j * 256 + t;         // i = n*128 + k  (16384 total)
            int n = i >> 7, k = i & 127;
            w1b[i] = f2b(W1[k * 128 + n]);
        }
    } else {
        for (int i = t; i < NB_BUCK * CSTR; i += 256) cursor[i] = 0;
        if (t == 0) dinv[N_NODES] = 0.f;                  // sentinel weight
        if (t < 128) h[(size_t)N_NODES * 128 + t] = 0;    // sentinel h row
    }
}

// ---- k_fuse1: UNCHANGED from R8 except cursor indexing (line-strided).
// Partition + GEMM1, 4 blocks/CU. ----
__global__ __launch_bounds__(256, 4) void k_fuse1(const int* __restrict__ ei,
                                                  int* __restrict__ cursor,
                                                  unsigned int* __restrict__ part,
                                                  const float* __restrict__ x,
                                                  const ushort* __restrict__ w1b,
                                                  ushort* __restrict__ h) {
    __shared__ __align__(16) ushort smem[128 * 136];   // 34816 B union
    int tid = threadIdx.x;

    if (blockIdx.x < NBLK_E) {
        // ---------- partition role (R1-exact) ----------
        int* lh    = (int*)smem;             // local hist, then local cursor (1563)
        int* lbase = lh + NB_BUCK;           // global base of this block's run (1563)
        for (int i = tid; i < NB_BUCK; i += 256) lh[i] = 0;
        __syncthreads();
        int e0 = blockIdx.x * EPB;
        int srcv[EPB / 256], dstv[EPB / 256];
        #pragma unroll
        for (int j = 0; j < EPB / 256; j++) {
            int e = e0 + j * 256 + tid;
            if (e < N_EDGES) {
                srcv[j] = ei[e];
                dstv[j] = ei[N_EDGES + e];
                atomicAdd(&lh[dstv[j] >> BUCK_SHIFT], 1);
            } else dstv[j] = -1;
        }
        __syncthreads();
        for (int i = tid; i < NB_BUCK; i += 256) {
            int c = lh[i];
            // one cursor per 64B line: ~350 atomics/line vs 5600 when packed
            lbase[i] = (c > 0) ? (i * CAP + atomicAdd(&cursor[i * CSTR], c)) : 0;
            lh[i] = 0;                        // becomes local cursor
        }
        __syncthreads();
        #pragma unroll
        for (int j = 0; j < EPB / 256; j++) {
            if (dstv[j] >= 0) {
                int bk = dstv[j] >> BUCK_SHIFT;
                int pos = lbase[bk] + atomicAdd(&lh[bk], 1);
                part[pos] = ((unsigned int)(dstv[j] & (BUCK_SZ - 1)) << 24) | (unsigned int)srcv[j];
            }
        }
        return;
    }

    // ---------- GEMM1 role: h = bf16(x @ W1), B direct from L2-hot w1b ----------
    typedef ushort (*tile_t)[136];
    tile_t As = (tile_t)smem;
    int row0 = (blockIdx.x - NBLK_E) * 128;
    const int M = N_NODES;

    #pragma unroll
    for (int i = 0; i < 16; i++) {
        int li = tid + i * 256;
        int r = li >> 5, c4 = li & 31;
        int grow = row0 + r; if (grow > M - 1) grow = M - 1;
        float4 v = *(const float4*)(x + (size_t)grow * 128 + c4 * 4);
        ushort4 o;
        o.x = f2b(v.x); o.y = f2b(v.y); o.z = f2b(v.z); o.w = f2b(v.w);
        *(ushort4*)&As[r][c4 * 4] = o;
    }
    __syncthreads();

    int wave = tid >> 6, lane = tid & 63;
    int lr = lane & 15, lq = lane >> 4;
    int wm0 = (wave & 1) * 64;
    int wn0 = (wave >> 1) * 64;

    f4_t acc[4][4];
    #pragma unroll
    for (int mi = 0; mi < 4; mi++)
        #pragma unroll
        for (int ni = 0; ni < 4; ni++) acc[mi][ni] = (f4_t){0.f, 0.f, 0.f, 0.f};

    #pragma unroll
    for (int kb = 0; kb < 4; kb++) {
        bf8_t af[4], bfr[4];
        #pragma unroll
        for (int mi = 0; mi < 4; mi++)
            af[mi] = *(const bf8_t*)&As[wm0 + mi * 16 + lr][kb * 32 + lq * 8];
        #pragma unroll
        for (int ni = 0; ni < 4; ni++)
            bfr[ni] = *(const bf8_t*)(w1b + (size_t)(wn0 + ni * 16 + lr) * 128 + kb * 32 + lq * 8);
        #pragma unroll
        for (int mi = 0; mi < 4; mi++)
            #pragma unroll
            for (int ni = 0; ni < 4; ni++)
                acc[mi][ni] = __builtin_amdgcn_mfma_f32_16x16x32_bf16(
                    af[mi], bfr[ni], acc[mi][ni], 0, 0, 0);
    }

    #pragma unroll
    for (int mi = 0; mi < 4; mi++) {
        #pragma unroll
        for (int r = 0; r < 4; r++) {
            int row = row0 + wm0 + mi * 16 + lq * 4 + r;
            if (row < M) {
                #pragma unroll
                for (int ni = 0; ni < 4; ni++)
                    h[(size_t)row * 128 + wn0 + ni * 16 + lr] = f2b(acc[mi][ni][r]);
            }
        }
    }
}

// ------- k_csr: UNCHANGED except cursor indexing. Per-bucket CSR finalize. -------
__global__ __launch_bounds__(256) void k_csr(const unsigned int* __restrict__ part,
                                             const int* __restrict__ cursor,
                                             int* __restrict__ offs,
                                             int* __restrict__ pcnt,
                                             float* __restrict__ dinv,
                                             int* __restrict__ ssrc) {
    __shared__ int ldeg[BUCK_SZ], lsc[BUCK_SZ], lcur[BUCK_SZ], sob[BUCK_SZ];
    __shared__ unsigned int stage[CAP];
    int t = threadIdx.x;
    int b = blockIdx.x;
    int rbeg = b * CAP;
    int cnt = cursor[b * CSTR];
    int node0 = b << BUCK_SHIFT;
    if (t < BUCK_SZ) ldeg[t] = 0;
    __syncthreads();
    for (int i = t; i < cnt; i += 256) {
        unsigned int u = part[rbeg + i];
        stage[i] = u;
        atomicAdd(&ldeg[u >> 24], 1);
    }
    __syncthreads();
    int v = 0, pv = 0;
    if (t < BUCK_SZ) {
        v = ldeg[t];
        pv = (v + 7) & ~7;
        lsc[t] = pv;
    }
    __syncthreads();
    for (int off = 1; off < BUCK_SZ; off <<= 1) {
        int add = 0;
        if (t < BUCK_SZ && t >= off) add = lsc[t - off];
        __syncthreads();
        if (t < BUCK_SZ) lsc[t] += add;
        __syncthreads();
    }
    if (t < BUCK_SZ) {
        int ob = b * PCAP + (lsc[t] - pv);
        sob[t] = ob;
        lcur[t] = 0;
        if (node0 + t < N_NODES) {
            offs[node0 + t] = ob;
            pcnt[node0 + t] = pv;
            dinv[node0 + t] = rsqrtf((float)(v + 1));    // +1: self-loop
        }
    }
    __syncthreads();
    for (int i = t; i < cnt; i += 256) {
        unsigned int u = stage[i];
        int d = u >> 24;
        int pos = atomicAdd(&lcur[d], 1);
        ssrc[sob[d] + pos] = (int)(u & 0xFFFFFFu);
    }
    if (t < BUCK_SZ)
        for (int i = v; i < pv; i++) ssrc[sob[t] + i] = N_NODES;  // sentinel pads
}

// ---- k_agg2: REVERTED to R8-exact (proven 70us floor; R9 pipeline regressed). ----
__global__ __launch_bounds__(256, 7) void k_agg2(const ushort* __restrict__ h,
                                                 const int* __restrict__ offs,
                                                 const int* __restrict__ pcnt,
                                                 const int* __restrict__ ssrc,
                                                 const float* __restrict__ dinv,
                                                 const float* __restrict__ b1,
                                                 const float* __restrict__ W2,
                                                 const float* __restrict__ b2,
                                                 float* __restrict__ out) {
    __shared__ ushort As[16][136];
    __shared__ ushort Bs[64][136];
    int tid = threadIdx.x;
    int wave = tid >> 6, lane = tid & 63;
    int base = blockIdx.x * 16;

    #pragma unroll
    for (int i = 0; i < 8; i++) {
        int li = tid + i * 256;
        int k = li >> 4, n4 = li & 15;
        float4 v = *(const float4*)(W2 + (size_t)k * 64 + n4 * 4);
        Bs[n4 * 4 + 0][k] = f2b(v.x);
        Bs[n4 * 4 + 1][k] = f2b(v.y);
        Bs[n4 * 4 + 2][k] = f2b(v.z);
        Bs[n4 * 4 + 3][k] = f2b(v.w);
    }

    const unsigned int* hp = (const unsigned int*)h;
    float2 bb = ((const float2*)b1)[lane];

    #pragma unroll 1
    for (int j = 0; j < 4; j++) {
        int r = wave * 4 + j;
        int n = base + r;
        int e0 = __builtin_amdgcn_readfirstlane(offs[n]);
        int iters = __builtin_amdgcn_readfirstlane(pcnt[n]) >> 3;
        const uint4* ip = (const uint4*)(ssrc + e0);

        float ax0 = 0.f, ay0 = 0.f, ax1 = 0.f, ay1 = 0.f;
        float ax2 = 0.f, ay2 = 0.f, ax3 = 0.f, ay3 = 0.f;
        uint4 i0, i1;
        if (iters > 0) { i0 = ip[0]; i1 = ip[1]; }
        for (int it = 0; it < iters; it++) {
            uint4 nx0 = i0, nx1 = i1;
            if (it + 1 < iters) { nx0 = ip[(it + 1) * 2]; nx1 = ip[(it + 1) * 2 + 1]; }
            int s0 = __builtin_amdgcn_readfirstlane((int)i0.x);
            int s1 = __builtin_amdgcn_readfirstlane((int)i0.y);
            int s2 = __builtin_amdgcn_readfirstlane((int)i0.z);
            int s3 = __builtin_amdgcn_readfirstlane((int)i0.w);
            int s4 = __builtin_amdgcn_readfirstlane((int)i1.x);
            int s5 = __builtin_amdgcn_readfirstlane((int)i1.y);
            int s6 = __builtin_amdgcn_readfirstlane((int)i1.z);
            int s7 = __builtin_amdgcn_readfirstlane((int)i1.w);
            unsigned int u0 = (hp + ((unsigned)s0 << 6))[lane];
            unsigned int u1 = (hp + ((unsigned)s1 << 6))[lane];
            unsigned int u2 = (hp + ((unsigned)s2 << 6))[lane];
            unsigned int u3 = (hp + ((unsigned)s3 << 6))[lane];
            unsigned int u4 = (hp + ((unsigned)s4 << 6))[lane];
            unsigned int u5 = (hp + ((unsigned)s5 << 6))[lane];
            unsigned int u6 = (hp + ((unsigned)s6 << 6))[lane];
            unsigned int u7 = (hp + ((unsigned)s7 << 6))[lane];
            float w0 = dinv[s0], w1 = dinv[s1], w2 = dinv[s2], w3 = dinv[s3];
            float w4 = dinv[s4], w5 = dinv[s5], w6 = dinv[s6], w7 = dinv[s7];
            ax0 = fmaf(b2f_lo(u0), w0, ax0); ay0 = fmaf(b2f_hi(u0), w0, ay0);
            ax1 = fmaf(b2f_lo(u1), w1, ax1); ay1 = fmaf(b2f_hi(u1), w1, ay1);
            ax2 = fmaf(b2f_lo(u2), w2, ax2); ay2 = fmaf(b2f_hi(u2), w2, ay2);
            ax3 = fmaf(b2f_lo(u3), w3, ax3); ay3 = fmaf(b2f_hi(u3), w3, ay3);
            ax0 = fmaf(b2f_lo(u4), w4, ax0); ay0 = fmaf(b2f_hi(u4), w4, ay0);
            ax1 = fmaf(b2f_lo(u5), w5, ax1); ay1 = fmaf(b2f_hi(u5), w5, ay1);
            ax2 = fmaf(b2f_lo(u6), w6, ax2); ay2 = fmaf(b2f_hi(u6), w6, ay2);
            ax3 = fmaf(b2f_lo(u7), w7, ax3); ay3 = fmaf(b2f_hi(u7), w7, ay3);
            i0 = nx0; i1 = nx1;
        }
        unsigned int us = hp[(size_t)n * 64 + lane];
        float dn = dinv[n];
        float rx = (ax0 + ax1 + ax2 + ax3 + b2f_lo(us) * dn) * dn + bb.x;
        float ry = (ay0 + ay1 + ay2 + ay3 + b2f_hi(us) * dn) * dn + bb.y;
        rx = rx > 0.f ? rx : 0.f;
        ry = ry > 0.f ? ry : 0.f;
        *(unsigned int*)&As[r][lane * 2] =
            ((unsigned int)f2b(ry) << 16) | (unsigned int)f2b(rx);
    }
    __syncthreads();

    int lr = lane & 15, lq = lane >> 4;
    f4_t acc = (f4_t){0.f, 0.f, 0.f, 0.f};
    #pragma unroll
    for (int kb = 0; kb < 4; kb++) {
        bf8_t af = *(const bf8_t*)&As[lr][kb * 32 + lq * 8];
        bf8_t bf = *(const bf8_t*)&Bs[wave * 16 + lr][kb * 32 + lq * 8];
        acc = __builtin_amdgcn_mfma_f32_16x16x32_bf16(af, bf, acc, 0, 0, 0);
    }
    int col = wave * 16 + lr;
    float bv = b2[col];
    #pragma unroll
    for (int r = 0; r < 4; r++) {
        int node = base + lq * 4 + r;
        out[(size_t)node * 64 + col] = acc[r] + bv;
    }
}

// ---------------- launch ----------------

extern "C" void kernel_launch(void* const* d_in, const int* in_sizes, int n_in,
                              void* d_out, int out_size, void* d_ws, size_t ws_size,
                              hipStream_t stream) {
    const float* x  = (const float*)d_in[0];
    const float* W1 = (const float*)d_in[1];
    const float* b1 = (const float*)d_in[2];
    const float* W2 = (const float*)d_in[3];
    const float* b2 = (const float*)d_in[4];
    const int*   ei = (const int*)d_in[5];
    float* out = (float*)d_out;

    char* w = (char*)d_ws;
    size_t off = 0;
    auto alloc = [&](size_t bytes) -> void* {
        void* p = w + off;
        off += (bytes + 255) & ~(size_t)255;
        return p;
    };
    ushort* h      = (ushort*)alloc((size_t)(N_NODES + 1) * HIDDEN * 2);  // +1 sentinel row
    float* dinv    = (float*)alloc((size_t)(N_NODES + 1) * 4);
    int*   offs    = (int*)alloc((size_t)N_NODES * 4);
    int*   pcnt    = (int*)alloc((size_t)N_NODES * 4);
    int*   ssrc    = (int*)alloc((size_t)NB_BUCK * PCAP * 4);
    unsigned int* part = (unsigned int*)alloc((size_t)NB_BUCK * CAP * 4);
    int*   cursor  = (int*)alloc((size_t)NB_BUCK * CSTR * 4);   // line-strided
    ushort* w1b    = (ushort*)alloc((size_t)HIDDEN * IN_DIM * 2);

    k_prep<<<9, 256, 0, stream>>>(W1, w1b, cursor, dinv, h);
    k_fuse1<<<NBLK_E + GB1, 256, 0, stream>>>(ei, cursor, part, x, w1b, h);
    k_csr<<<NB_BUCK, 256, 0, stream>>>(part, cursor, offs, pcnt, dinv, ssrc);
    k_agg2<<<N_NODES / 16, 256, 0, stream>>>(h, offs, pcnt, ssrc, dinv, b1, W2, b2, out);
}

// Round 11
// 203.945 us; speedup vs baseline: 1.0942x; 1.0942x over previous
//
#include <hip/hip_runtime.h>

#define N_NODES 100000
#define N_EDGES 1600000
#define IN_DIM  128
#define HIDDEN  128
#define OUT_DIM 64

#define BUCK_SHIFT 6                          // 64-node buckets
#define BUCK_SZ    64
#define NB_BUCK ((N_NODES + BUCK_SZ - 1) / BUCK_SZ)   // 1563 buckets
#define EPB 4096                              // edges per partition block (R1-proven)
#define NBLK_E ((N_EDGES + EPB - 1) / EPB)    // 391 partition blocks
#define GB1 ((N_NODES + 127) / 128)           // 782 GEMM1 blocks
#define CAP 1536                              // bucket capacity (mean 1024 + 16 sigma)
#define PCAP 1984                             // padded capacity, mult of 8

typedef __attribute__((ext_vector_type(8))) short bf8_t;   // 8 x bf16 (4 VGPRs)
typedef __attribute__((ext_vector_type(4))) float f4_t;    // MFMA accumulator

__device__ __forceinline__ ushort f2b(float f) {           // fp32 -> bf16 RNE
    unsigned int u = __float_as_uint(f);
    u += 0x7fffu + ((u >> 16) & 1u);
    return (ushort)(u >> 16);
}
__device__ __forceinline__ float b2f_lo(unsigned int u) { return __uint_as_float(u << 16); }
__device__ __forceinline__ float b2f_hi(unsigned int u) { return __uint_as_float(u & 0xffff0000u); }

// ---- k_prep: w1b conversion + cursor zero + sentinels (R8-exact; packed cursor) ----
__global__ __launch_bounds__(256) void k_prep(const float* __restrict__ W1,
                                              ushort* __restrict__ w1b,
                                              int* __restrict__ cursor,
                                              float* __restrict__ dinv,
                                              ushort* __restrict__ h) {
    int b = blockIdx.x, t = threadIdx.x;
    if (b < 8) {
        int start = b * 2048;
        #pragma unroll
        for (int j = 0; j < 8; j++) {
            int i = start + j * 256 + t;         // i = n*128 + k  (16384 total)
            int n = i >> 7, k = i & 127;
            w1b[i] = f2b(W1[k * 128 + n]);
        }
    } else {
        for (int i = t; i < NB_BUCK; i += 256) cursor[i] = 0;
        if (t == 0) dinv[N_NODES] = 0.f;                  // sentinel weight
        if (t < 128) h[(size_t)N_NODES * 128 + t] = 0;    // sentinel h row
    }
}

// ---- k_fuse1: R8-exact (packed cursor restored; R10's padding falsified). ----
__global__ __launch_bounds__(256, 4) void k_fuse1(const int* __restrict__ ei,
                                                  int* __restrict__ cursor,
                                                  unsigned int* __restrict__ part,
                                                  const float* __restrict__ x,
                                                  const ushort* __restrict__ w1b,
                                                  ushort* __restrict__ h) {
    __shared__ __align__(16) ushort smem[128 * 136];   // 34816 B union
    int tid = threadIdx.x;

    if (blockIdx.x < NBLK_E) {
        // ---------- partition role (R1-exact) ----------
        int* lh    = (int*)smem;             // local hist, then local cursor (1563)
        int* lbase = lh + NB_BUCK;           // global base of this block's run (1563)
        for (int i = tid; i < NB_BUCK; i += 256) lh[i] = 0;
        __syncthreads();
        int e0 = blockIdx.x * EPB;
        int srcv[EPB / 256], dstv[EPB / 256];
        #pragma unroll
        for (int j = 0; j < EPB / 256; j++) {
            int e = e0 + j * 256 + tid;
            if (e < N_EDGES) {
                srcv[j] = ei[e];
                dstv[j] = ei[N_EDGES + e];
                atomicAdd(&lh[dstv[j] >> BUCK_SHIFT], 1);
            } else dstv[j] = -1;
        }
        __syncthreads();
        for (int i = tid; i < NB_BUCK; i += 256) {
            int c = lh[i];
            lbase[i] = (c > 0) ? (i * CAP + atomicAdd(&cursor[i], c)) : 0;
            lh[i] = 0;                        // becomes local cursor
        }
        __syncthreads();
        #pragma unroll
        for (int j = 0; j < EPB / 256; j++) {
            if (dstv[j] >= 0) {
                int bk = dstv[j] >> BUCK_SHIFT;
                int pos = lbase[bk] + atomicAdd(&lh[bk], 1);
                part[pos] = ((unsigned int)(dstv[j] & (BUCK_SZ - 1)) << 24) | (unsigned int)srcv[j];
            }
        }
        return;
    }

    // ---------- GEMM1 role: h = bf16(x @ W1), B direct from L2-hot w1b ----------
    typedef ushort (*tile_t)[136];
    tile_t As = (tile_t)smem;
    int row0 = (blockIdx.x - NBLK_E) * 128;
    const int M = N_NODES;

    #pragma unroll
    for (int i = 0; i < 16; i++) {
        int li = tid + i * 256;
        int r = li >> 5, c4 = li & 31;
        int grow = row0 + r; if (grow > M - 1) grow = M - 1;
        float4 v = *(const float4*)(x + (size_t)grow * 128 + c4 * 4);
        ushort4 o;
        o.x = f2b(v.x); o.y = f2b(v.y); o.z = f2b(v.z); o.w = f2b(v.w);
        *(ushort4*)&As[r][c4 * 4] = o;
    }
    __syncthreads();

    int wave = tid >> 6, lane = tid & 63;
    int lr = lane & 15, lq = lane >> 4;
    int wm0 = (wave & 1) * 64;
    int wn0 = (wave >> 1) * 64;

    f4_t acc[4][4];
    #pragma unroll
    for (int mi = 0; mi < 4; mi++)
        #pragma unroll
        for (int ni = 0; ni < 4; ni++) acc[mi][ni] = (f4_t){0.f, 0.f, 0.f, 0.f};

    #pragma unroll
    for (int kb = 0; kb < 4; kb++) {
        bf8_t af[4], bfr[4];
        #pragma unroll
        for (int mi = 0; mi < 4; mi++)
            af[mi] = *(const bf8_t*)&As[wm0 + mi * 16 + lr][kb * 32 + lq * 8];
        #pragma unroll
        for (int ni = 0; ni < 4; ni++)
            bfr[ni] = *(const bf8_t*)(w1b + (size_t)(wn0 + ni * 16 + lr) * 128 + kb * 32 + lq * 8);
        #pragma unroll
        for (int mi = 0; mi < 4; mi++)
            #pragma unroll
            for (int ni = 0; ni < 4; ni++)
                acc[mi][ni] = __builtin_amdgcn_mfma_f32_16x16x32_bf16(
                    af[mi], bfr[ni], acc[mi][ni], 0, 0, 0);
    }

    #pragma unroll
    for (int mi = 0; mi < 4; mi++) {
        #pragma unroll
        for (int r = 0; r < 4; r++) {
            int row = row0 + wm0 + mi * 16 + lq * 4 + r;
            if (row < M) {
                #pragma unroll
                for (int ni = 0; ni < 4; ni++)
                    h[(size_t)row * 128 + wn0 + ni * 16 + lr] = f2b(acc[mi][ni][r]);
            }
        }
    }
}

// ------- k_csr: REWORKED output path. Scatter into LDS `sorted` (pre-filled
// with sentinel -> pads free), then dump to ssrc with contiguous int4 stores.
// Old path: 1.6M scattered 4B stores = ~100MB of 64B-line write traffic.
// New path: ~8MB coalesced. ssrc contents bit-identical; agg2 untouched. -------
__global__ __launch_bounds__(256) void k_csr(const unsigned int* __restrict__ part,
                                             const int* __restrict__ cursor,
                                             int* __restrict__ offs,
                                             int* __restrict__ pcnt,
                                             float* __restrict__ dinv,
                                             int* __restrict__ ssrc) {
    __shared__ int ldeg[BUCK_SZ], lsc[BUCK_SZ], lcur[BUCK_SZ], sob[BUCK_SZ];
    __shared__ unsigned int stage[CAP];
    __shared__ int sorted[PCAP];          // bucket-local reordered srcs (7936 B)
    int t = threadIdx.x;
    int b = blockIdx.x;
    int rbeg = b * CAP;
    int cnt = cursor[b];
    int node0 = b << BUCK_SHIFT;
    if (t < BUCK_SZ) ldeg[t] = 0;
    for (int i = t; i < PCAP; i += 256) sorted[i] = N_NODES;   // sentinel pre-fill
    __syncthreads();
    for (int i = t; i < cnt; i += 256) {
        unsigned int u = part[rbeg + i];
        stage[i] = u;
        atomicAdd(&ldeg[u >> 24], 1);
    }
    __syncthreads();
    int v = 0, pv = 0;
    if (t < BUCK_SZ) {
        v = ldeg[t];
        pv = (v + 7) & ~7;
        lsc[t] = pv;
    }
    __syncthreads();
    for (int off = 1; off < BUCK_SZ; off <<= 1) {
        int add = 0;
        if (t < BUCK_SZ && t >= off) add = lsc[t - off];
        __syncthreads();
        if (t < BUCK_SZ) lsc[t] += add;
        __syncthreads();
    }
    if (t < BUCK_SZ) {
        int lob = lsc[t] - pv;            // LOCAL padded offset within bucket
        sob[t] = lob;
        lcur[t] = 0;
        if (node0 + t < N_NODES) {
            offs[node0 + t] = b * PCAP + lob;
            pcnt[node0 + t] = pv;
            dinv[node0 + t] = rsqrtf((float)(v + 1));    // +1: self-loop
        }
    }
    __syncthreads();
    for (int i = t; i < cnt; i += 256) {
        unsigned int u = stage[i];
        int d = u >> 24;
        int pos = atomicAdd(&lcur[d], 1);
        sorted[sob[d] + pos] = (int)(u & 0xFFFFFFu);     // LDS scatter (cheap)
    }
    __syncthreads();
    int total = lsc[BUCK_SZ - 1];         // padded bucket total, mult of 8
    int4* dst4 = (int4*)(ssrc + (size_t)b * PCAP);       // 16B-aligned
    const int4* src4 = (const int4*)sorted;
    for (int i = t; i < (total >> 2); i += 256) dst4[i] = src4[i];   // coalesced dump
}

// ---- k_agg2: R8-exact (proven 70us floor). Aggregation + fused GEMM2. ----
__global__ __launch_bounds__(256, 7) void k_agg2(const ushort* __restrict__ h,
                                                 const int* __restrict__ offs,
                                                 const int* __restrict__ pcnt,
                                                 const int* __restrict__ ssrc,
                                                 const float* __restrict__ dinv,
                                                 const float* __restrict__ b1,
                                                 const float* __restrict__ W2,
                                                 const float* __restrict__ b2,
                                                 float* __restrict__ out) {
    __shared__ ushort As[16][136];
    __shared__ ushort Bs[64][136];
    int tid = threadIdx.x;
    int wave = tid >> 6, lane = tid & 63;
    int base = blockIdx.x * 16;

    #pragma unroll
    for (int i = 0; i < 8; i++) {
        int li = tid + i * 256;
        int k = li >> 4, n4 = li & 15;
        float4 v = *(const float4*)(W2 + (size_t)k * 64 + n4 * 4);
        Bs[n4 * 4 + 0][k] = f2b(v.x);
        Bs[n4 * 4 + 1][k] = f2b(v.y);
        Bs[n4 * 4 + 2][k] = f2b(v.z);
        Bs[n4 * 4 + 3][k] = f2b(v.w);
    }

    const unsigned int* hp = (const unsigned int*)h;
    float2 bb = ((const float2*)b1)[lane];

    #pragma unroll 1
    for (int j = 0; j < 4; j++) {
        int r = wave * 4 + j;
        int n = base + r;
        int e0 = __builtin_amdgcn_readfirstlane(offs[n]);
        int iters = __builtin_amdgcn_readfirstlane(pcnt[n]) >> 3;
        const uint4* ip = (const uint4*)(ssrc + e0);

        float ax0 = 0.f, ay0 = 0.f, ax1 = 0.f, ay1 = 0.f;
        float ax2 = 0.f, ay2 = 0.f, ax3 = 0.f, ay3 = 0.f;
        uint4 i0, i1;
        if (iters > 0) { i0 = ip[0]; i1 = ip[1]; }
        for (int it = 0; it < iters; it++) {
            uint4 nx0 = i0, nx1 = i1;
            if (it + 1 < iters) { nx0 = ip[(it + 1) * 2]; nx1 = ip[(it + 1) * 2 + 1]; }
            int s0 = __builtin_amdgcn_readfirstlane((int)i0.x);
            int s1 = __builtin_amdgcn_readfirstlane((int)i0.y);
            int s2 = __builtin_amdgcn_readfirstlane((int)i0.z);
            int s3 = __builtin_amdgcn_readfirstlane((int)i0.w);
            int s4 = __builtin_amdgcn_readfirstlane((int)i1.x);
            int s5 = __builtin_amdgcn_readfirstlane((int)i1.y);
            int s6 = __builtin_amdgcn_readfirstlane((int)i1.z);
            int s7 = __builtin_amdgcn_readfirstlane((int)i1.w);
            unsigned int u0 = (hp + ((unsigned)s0 << 6))[lane];
            unsigned int u1 = (hp + ((unsigned)s1 << 6))[lane];
            unsigned int u2 = (hp + ((unsigned)s2 << 6))[lane];
            unsigned int u3 = (hp + ((unsigned)s3 << 6))[lane];
            unsigned int u4 = (hp + ((unsigned)s4 << 6))[lane];
            unsigned int u5 = (hp + ((unsigned)s5 << 6))[lane];
            unsigned int u6 = (hp + ((unsigned)s6 << 6))[lane];
            unsigned int u7 = (hp + ((unsigned)s7 << 6))[lane];
            float w0 = dinv[s0], w1 = dinv[s1], w2 = dinv[s2], w3 = dinv[s3];
            float w4 = dinv[s4], w5 = dinv[s5], w6 = dinv[s6], w7 = dinv[s7];
            ax0 = fmaf(b2f_lo(u0), w0, ax0); ay0 = fmaf(b2f_hi(u0), w0, ay0);
            ax1 = fmaf(b2f_lo(u1), w1, ax1); ay1 = fmaf(b2f_hi(u1), w1, ay1);
            ax2 = fmaf(b2f_lo(u2), w2, ax2); ay2 = fmaf(b2f_hi(u2), w2, ay2);
            ax3 = fmaf(b2f_lo(u3), w3, ax3); ay3 = fmaf(b2f_hi(u3), w3, ay3);
            ax0 = fmaf(b2f_lo(u4), w4, ax0); ay0 = fmaf(b2f_hi(u4), w4, ay0);
            ax1 = fmaf(b2f_lo(u5), w5, ax1); ay1 = fmaf(b2f_hi(u5), w5, ay1);
            ax2 = fmaf(b2f_lo(u6), w6, ax2); ay2 = fmaf(b2f_hi(u6), w6, ay2);
            ax3 = fmaf(b2f_lo(u7), w7, ax3); ay3 = fmaf(b2f_hi(u7), w7, ay3);
            i0 = nx0; i1 = nx1;
        }
        unsigned int us = hp[(size_t)n * 64 + lane];
        float dn = dinv[n];
        float rx = (ax0 + ax1 + ax2 + ax3 + b2f_lo(us) * dn) * dn + bb.x;
        float ry = (ay0 + ay1 + ay2 + ay3 + b2f_hi(us) * dn) * dn + bb.y;
        rx = rx > 0.f ? rx : 0.f;
        ry = ry > 0.f ? ry : 0.f;
        *(unsigned int*)&As[r][lane * 2] =
            ((unsigned int)f2b(ry) << 16) | (unsigned int)f2b(rx);
    }
    __syncthreads();

    int lr = lane & 15, lq = lane >> 4;
    f4_t acc = (f4_t){0.f, 0.f, 0.f, 0.f};
    #pragma unroll
    for (int kb = 0; kb < 4; kb++) {
        bf8_t af = *(const bf8_t*)&As[lr][kb * 32 + lq * 8];
        bf8_t bf = *(const bf8_t*)&Bs[wave * 16 + lr][kb * 32 + lq * 8];
        acc = __builtin_amdgcn_mfma_f32_16x16x32_bf16(af, bf, acc, 0, 0, 0);
    }
    int col = wave * 16 + lr;
    float bv = b2[col];
    #pragma unroll
    for (int r = 0; r < 4; r++) {
        int node = base + lq * 4 + r;
        out[(size_t)node * 64 + col] = acc[r] + bv;
    }
}

// ---------------- launch ----------------

extern "C" void kernel_launch(void* const* d_in, const int* in_sizes, int n_in,
                              void* d_out, int out_size, void* d_ws, size_t ws_size,
                              hipStream_t stream) {
    const float* x  = (const float*)d_in[0];
    const float* W1 = (const float*)d_in[1];
    const float* b1 = (const float*)d_in[2];
    const float* W2 = (const float*)d_in[3];
    const float* b2 = (const float*)d_in[4];
    const int*   ei = (const int*)d_in[5];
    float* out = (float*)d_out;

    char* w = (char*)d_ws;
    size_t off = 0;
    auto alloc = [&](size_t bytes) -> void* {
        void* p = w + off;
        off += (bytes + 255) & ~(size_t)255;
        return p;
    };
    ushort* h      = (ushort*)alloc((size_t)(N_NODES + 1) * HIDDEN * 2);  // +1 sentinel row
    float* dinv    = (float*)alloc((size_t)(N_NODES + 1) * 4);
    int*   offs    = (int*)alloc((size_t)N_NODES * 4);
    int*   pcnt    = (int*)alloc((size_t)N_NODES * 4);
    int*   ssrc    = (int*)alloc((size_t)NB_BUCK * PCAP * 4);
    unsigned int* part = (unsigned int*)alloc((size_t)NB_BUCK * CAP * 4);
    int*   cursor  = (int*)alloc((size_t)NB_BUCK * 4);
    ushort* w1b    = (ushort*)alloc((size_t)HIDDEN * IN_DIM * 2);

    k_prep<<<9, 256, 0, stream>>>(W1, w1b, cursor, dinv, h);
    k_fuse1<<<NBLK_E + GB1, 256, 0, stream>>>(ei, cursor, part, x, w1b, h);
    k_csr<<<NB_BUCK, 256, 0, stream>>>(part, cursor, offs, pcnt, dinv, ssrc);
    k_agg2<<<N_NODES / 16, 256, 0, stream>>>(h, offs, pcnt, ssrc, dinv, b1, W2, b2, out);
}